// Round 7
// baseline (266.004 us; speedup 1.0000x reference)
//
#include <hip/hip_runtime.h>
#include <hip/hip_fp16.h>

static constexpr int D = 128;
static constexpr int RPB_LOG = 10;           // 1024 rows per bin
static constexpr int RPB = 1 << RPB_LOG;
static constexpr int MAX_BINS = 1024;        // supports N <= 1M rows
static constexpr int CHUNK = 8192;           // edges per binA/binCount block

// ---------------- pass 0: count edges per bin ----------------
__global__ void binCount(const int* __restrict__ erow, int* __restrict__ bin_cnt,
                         int E, int nbins) {
    __shared__ int hist[MAX_BINS];
    int t = threadIdx.x;                       // 256
    int e0 = blockIdx.x * CHUNK;
    for (int i = t; i < nbins; i += 256) hist[i] = 0;
    __syncthreads();
    for (int k = 0; k < CHUNK / 256; ++k) {
        int e = e0 + t + k * 256;
        if (e < E) atomicAdd(&hist[erow[e] >> RPB_LOG], 1);
    }
    __syncthreads();
    for (int b = t; b < nbins; b += 256)
        if (hist[b]) atomicAdd(&bin_cnt[b], hist[b]);
}

// ---------------- pass 0b: exclusive scan of bin counts ----------------
__global__ void scanBins(const int* __restrict__ bin_cnt, int* __restrict__ bin_base,
                         int* __restrict__ gcur, int nbins, int E) {
    __shared__ int sm[MAX_BINS];
    int t = threadIdx.x;                       // 1024
    int v = (t < nbins) ? bin_cnt[t] : 0;
    sm[t] = v;
    __syncthreads();
    for (int off = 1; off < MAX_BINS; off <<= 1) {
        int x = sm[t];
        int y = (t >= off) ? sm[t - off] : 0;
        __syncthreads();
        sm[t] = x + y;
        __syncthreads();
    }
    if (t < nbins) {
        int excl = sm[t] - v;
        bin_base[t] = excl;
        gcur[t] = excl;
    }
    if (t == 0) bin_base[nbins] = E;
}

// ---------------- pass A: scatter (row,col) pairs into bin slices ----------------
__global__ void binA(const int* __restrict__ erow, const int* __restrict__ ecol,
                     int* __restrict__ gcur, int2* __restrict__ tmp, int E, int nbins) {
    __shared__ int hist[MAX_BINS];
    __shared__ int base[MAX_BINS];
    __shared__ int lcur[MAX_BINS];
    int t = threadIdx.x;                       // 256
    int e0 = blockIdx.x * CHUNK;
    for (int i = t; i < nbins; i += 256) { hist[i] = 0; lcur[i] = 0; }
    __syncthreads();
    for (int k = 0; k < CHUNK / 256; ++k) {
        int e = e0 + t + k * 256;
        if (e < E) atomicAdd(&hist[erow[e] >> RPB_LOG], 1);
    }
    __syncthreads();
    for (int b = t; b < nbins; b += 256)
        base[b] = hist[b] ? atomicAdd(&gcur[b], hist[b]) : 0;
    __syncthreads();
    for (int k = 0; k < CHUNK / 256; ++k) {
        int e = e0 + t + k * 256;
        if (e < E) {
            int r = erow[e];
            int b = r >> RPB_LOG;
            int pos = base[b] + atomicAdd(&lcur[b], 1);
            tmp[pos] = make_int2(r, ecol[e]);
        }
    }
}

// ---------------- pass B: per-bin degree hist + scan + order ----------------
__global__ void binB(const int2* __restrict__ tmp, const int* __restrict__ bin_base,
                     int* __restrict__ row_ptr, float* __restrict__ dinv,
                     float* __restrict__ rdinv, int* __restrict__ col_s,
                     int N, int E, int nbins) {
    __shared__ int cnt[RPB];
    __shared__ int sm[RPB];
    __shared__ int cur[RPB];
    int b = blockIdx.x;
    int r0 = b << RPB_LOG;
    int t = threadIdx.x;                       // 1024
    cnt[t] = 0;
    __syncthreads();
    int start = bin_base[b];
    int end = bin_base[b + 1];
    for (int p = start + t; p < end; p += RPB)
        atomicAdd(&cnt[tmp[p].x - r0], 1);
    __syncthreads();
    int v = cnt[t];
    sm[t] = v;
    __syncthreads();
    for (int off = 1; off < RPB; off <<= 1) {
        int x = sm[t];
        int y = (t >= off) ? sm[t - off] : 0;
        __syncthreads();
        sm[t] = x + y;
        __syncthreads();
    }
    int rp = start + sm[t] - v;
    int r = r0 + t;
    if (r < N) {
        row_ptr[r] = rp;
        dinv[r]  = (v > 0) ? rsqrtf((float)v) : 0.0f;
        rdinv[r] = (v > 0) ? sqrtf((float)v) : 0.0f;
    }
    if (b == 0 && t == 0) row_ptr[N] = E;
    cur[t] = rp;
    __syncthreads();
    for (int p = start + t; p < end; p += RPB) {
        int2 pr = tmp[p];
        int pos = atomicAdd(&cur[pr.x - r0], 1);
        col_s[pos] = pr.y;
    }
}

// ---------------- init: g0 = fp16(dinv*x) ----------------
__global__ void init_g(const float4* __restrict__ vsrc,
                       const float4* __restrict__ dsrc,
                       const float* __restrict__ dinv,
                       __half2* __restrict__ g,
                       long nv4, long total4) {
    long i = (long)blockIdx.x * blockDim.x + threadIdx.x;
    long stride = (long)gridDim.x * blockDim.x;
    for (; i < total4; i += stride) {
        float4 v = (i < nv4) ? vsrc[i] : dsrc[i - nv4];
        float w = dinv[i >> 5];               // 32 float4 per row
        g[i * 2]     = __floats2half2_rn(w * v.x, w * v.y);
        g[i * 2 + 1] = __floats2half2_rn(w * v.z, w * v.w);
    }
}

// Gather core: 4 lane-groups of 16; each group fetches whole 256B g-rows
// (one dwordx4/lane), 2 rows in flight per group. acc[8] = per-lane features
// [sub*8, sub*8+8) summed over cols == group (mod 4); butterfly at the end.
__device__ __forceinline__ void gather_rows(const int* __restrict__ col_s,
                                            int start, int end,
                                            const __half* __restrict__ gsrc,
                                            int grp, int sub, float acc[8]) {
    int j = start + grp;
    for (; j + 4 < end; j += 8) {
        int c0 = col_s[j];
        int c1 = col_s[j + 4];
        float4 v0 = ((const float4*)(gsrc + (long)c0 * D))[sub];
        float4 v1 = ((const float4*)(gsrc + (long)c1 * D))[sub];
        const __half2* h0 = (const __half2*)&v0;
        const __half2* h1 = (const __half2*)&v1;
#pragma unroll
        for (int k = 0; k < 4; ++k) {
            float2 f0 = __half22float2(h0[k]);
            float2 f1 = __half22float2(h1[k]);
            acc[2 * k]     += f0.x + f1.x;
            acc[2 * k + 1] += f0.y + f1.y;
        }
    }
    if (j < end) {
        int c = col_s[j];
        float4 v = ((const float4*)(gsrc + (long)c * D))[sub];
        const __half2* h = (const __half2*)&v;
#pragma unroll
        for (int k = 0; k < 4; ++k) {
            float2 f = __half22float2(h[k]);
            acc[2 * k]     += f.x;
            acc[2 * k + 1] += f.y;
        }
    }
#pragma unroll
    for (int k = 0; k < 8; ++k) {
        acc[k] += __shfl_xor(acc[k], 16, 64);
        acc[k] += __shfl_xor(acc[k], 32, 64);
    }
}

// ---------------- mid layers: gnext = fp16(dinv^2 * sum_c g[c]) ----------------
__global__ void spmm_mid(const int* __restrict__ row_ptr, const int* __restrict__ col_s,
                         const float* __restrict__ dinv, const __half* __restrict__ g,
                         __half* __restrict__ gnext, int N) {
    int gid = blockIdx.x * blockDim.x + threadIdx.x;
    int r = __builtin_amdgcn_readfirstlane(gid >> 6);
    if (r >= N) return;
    int lane = gid & 63;
    int grp = lane >> 4, sub = lane & 15;
    int start = row_ptr[r], end = row_ptr[r + 1];
    float acc[8] = {0, 0, 0, 0, 0, 0, 0, 0};
    gather_rows(col_s, start, end, g, grp, sub, acc);
    if (lane < 16) {
        float dr = dinv[r];
        float d2 = dr * dr;
        float4 st;
        __half2* hs = (__half2*)&st;
#pragma unroll
        for (int k = 0; k < 4; ++k)
            hs[k] = __floats2half2_rn(d2 * acc[2 * k], d2 * acc[2 * k + 1]);
        ((float4*)(gnext + (long)r * D))[sub] = st;
    }
}

// -------- final layer: out = 0.25*(x + (g1+g2)*rdinv + dinv*sum g2[c]) --------
__global__ void spmm_final(const int* __restrict__ row_ptr, const int* __restrict__ col_s,
                           const float* __restrict__ dinv, const float* __restrict__ rdinv,
                           const __half* __restrict__ g2,    // gather source
                           const __half* __restrict__ g1,    // layer-1 output
                           const float* __restrict__ xv, const float* __restrict__ xd,
                           int nvRows, float* __restrict__ out, int N) {
    int gid = blockIdx.x * blockDim.x + threadIdx.x;
    int r = __builtin_amdgcn_readfirstlane(gid >> 6);
    if (r >= N) return;
    int lane = gid & 63;
    int grp = lane >> 4, sub = lane & 15;
    int start = row_ptr[r], end = row_ptr[r + 1];
    float acc[8] = {0, 0, 0, 0, 0, 0, 0, 0};
    gather_rows(col_s, start, end, g2, grp, sub, acc);
    if (lane < 16) {
        float dr = dinv[r];
        float rd = rdinv[r];
        const float* xbase = (r < nvRows) ? (xv + (long)r * D)
                                          : (xd + (long)(r - nvRows) * D);
        float4 x0 = ((const float4*)xbase)[sub * 2];
        float4 x1 = ((const float4*)xbase)[sub * 2 + 1];
        float4 p1v = ((const float4*)(g1 + (long)r * D))[sub];
        float4 p2v = ((const float4*)(g2 + (long)r * D))[sub];
        const __half2* h1 = (const __half2*)&p1v;
        const __half2* h2 = (const __half2*)&p2v;
        float xr[8] = {x0.x, x0.y, x0.z, x0.w, x1.x, x1.y, x1.z, x1.w};
        float o[8];
#pragma unroll
        for (int k = 0; k < 4; ++k) {
            float2 f1 = __half22float2(h1[k]);
            float2 f2 = __half22float2(h2[k]);
            o[2 * k]     = 0.25f * (xr[2 * k]     + (f1.x + f2.x) * rd + dr * acc[2 * k]);
            o[2 * k + 1] = 0.25f * (xr[2 * k + 1] + (f1.y + f2.y) * rd + dr * acc[2 * k + 1]);
        }
        float4* ob = (float4*)(out + (long)r * D);
        ob[sub * 2]     = make_float4(o[0], o[1], o[2], o[3]);
        ob[sub * 2 + 1] = make_float4(o[4], o[5], o[6], o[7]);
    }
}

// ---------------- fallback (atomic scatter path, fp32) ----------------
__global__ void init_copy(const float4* __restrict__ vsrc,
                          const float4* __restrict__ dsrc,
                          float4* __restrict__ h,
                          float4* __restrict__ acc,
                          long nv4, long total4) {
    long i = (long)blockIdx.x * blockDim.x + threadIdx.x;
    long stride = (long)gridDim.x * blockDim.x;
    for (; i < total4; i += stride) {
        float4 v = (i < nv4) ? vsrc[i] : dsrc[i - nv4];
        h[i] = v;
        acc[i] = v;
    }
}

__global__ void spmm_scatter(const int* __restrict__ erow, const int* __restrict__ ecol,
                             const float* __restrict__ eval, const float* __restrict__ h,
                             float* __restrict__ hnext, int E) {
    long tid = (long)blockIdx.x * blockDim.x + threadIdx.x;
    int e = (int)(tid >> 6);
    if (e >= E) return;
    int lane = (int)(tid & 63);
    int r = erow[e], c = ecol[e];
    float w = eval[e];
    const float2* src = reinterpret_cast<const float2*>(h + (long)c * D);
    float2 m = src[lane];
    float* dst = hnext + (long)r * D + lane * 2;
    atomicAdd(dst, w * m.x);
    atomicAdd(dst + 1, w * m.y);
}

__global__ void add_scale(float4* __restrict__ acc, const float4* __restrict__ b,
                          float s, long total4) {
    long i = (long)blockIdx.x * blockDim.x + threadIdx.x;
    long stride = (long)gridDim.x * blockDim.x;
    for (; i < total4; i += stride) {
        float4 a = acc[i];
        float4 v = b[i];
        a.x = (a.x + v.x) * s;
        a.y = (a.y + v.y) * s;
        a.z = (a.z + v.z) * s;
        a.w = (a.w + v.w) * s;
        acc[i] = a;
    }
}

extern "C" void kernel_launch(void* const* d_in, const int* in_sizes, int n_in,
                              void* d_out, int out_size, void* d_ws, size_t ws_size,
                              hipStream_t stream) {
    const int*   erow = (const int*)d_in[0];
    const int*   ecol = (const int*)d_in[1];
    const float* eval = (const float*)d_in[2];
    const float* vemb = (const float*)d_in[3];
    const float* demb = (const float*)d_in[4];

    int  E   = in_sizes[0];
    long nvD = in_sizes[3];
    long ndD = in_sizes[4];
    long ND  = nvD + ndD;
    int  N   = (int)(ND / D);
    int  nvRows = (int)(nvD / D);
    int  nbins = (N + RPB - 1) >> RPB_LOG;

    float* out = (float*)d_out;

    // ws layout (fast path)
    char* w = (char*)d_ws;
    __half* gA = (__half*)w;  w += (size_t)ND * sizeof(__half);   // g0
    __half* gB = (__half*)w;  w += (size_t)ND * sizeof(__half);   // g1
    __half* gC = (__half*)w;  w += (size_t)ND * sizeof(__half);   // g2
    int* col_s    = (int*)w;  w += (size_t)E * sizeof(int);
    int2* tmp     = (int2*)w; w += (size_t)E * sizeof(int2);
    int* row_ptr  = (int*)w;  w += (size_t)(N + 1) * sizeof(int);
    int* bin_cnt  = (int*)w;  w += MAX_BINS * sizeof(int);
    int* bin_base = (int*)w;  w += (MAX_BINS + 1) * sizeof(int);
    int* gcur     = (int*)w;  w += MAX_BINS * sizeof(int);
    float* dinv   = (float*)w; w += (size_t)N * sizeof(float);
    float* rdinv  = (float*)w; w += (size_t)N * sizeof(float);
    size_t needed = (size_t)(w - (char*)d_ws);

    long total4 = ND / 4;
    long nv4    = nvD / 4;
    const int blk = 256;
    const int copyGrid = 2048;

    if (needed <= ws_size && nbins <= MAX_BINS) {
        // ---------- CSR build (bin-local, no global row scans) ----------
        hipMemsetAsync(bin_cnt, 0, MAX_BINS * sizeof(int), stream);
        int nblkA = (E + CHUNK - 1) / CHUNK;
        hipLaunchKernelGGL(binCount, dim3(nblkA), dim3(256), 0, stream,
                           erow, bin_cnt, E, nbins);
        hipLaunchKernelGGL(scanBins, dim3(1), dim3(1024), 0, stream,
                           bin_cnt, bin_base, gcur, nbins, E);
        hipLaunchKernelGGL(binA, dim3(nblkA), dim3(256), 0, stream,
                           erow, ecol, gcur, tmp, E, nbins);
        hipLaunchKernelGGL(binB, dim3(nbins), dim3(RPB), 0, stream,
                           tmp, bin_base, row_ptr, dinv, rdinv, col_s, N, E, nbins);

        // ---------- init: g0 = fp16(dinv*x) ----------
        hipLaunchKernelGGL(init_g, dim3(copyGrid), dim3(blk), 0, stream,
                           (const float4*)vemb, (const float4*)demb, dinv,
                           (__half2*)gA, nv4, total4);

        // ---------- layers ----------
        int rgrid = (int)(((long)N * 64 + blk - 1) / blk);
        hipLaunchKernelGGL(spmm_mid, dim3(rgrid), dim3(blk), 0, stream,
                           row_ptr, col_s, dinv, gA, gB, N);
        hipLaunchKernelGGL(spmm_mid, dim3(rgrid), dim3(blk), 0, stream,
                           row_ptr, col_s, dinv, gB, gC, N);
        hipLaunchKernelGGL(spmm_final, dim3(rgrid), dim3(blk), 0, stream,
                           row_ptr, col_s, dinv, rdinv, gC, gB,
                           vemb, demb, nvRows, out, N);
    } else {
        // ---------- fallback: atomic scatter path (fp32) ----------
        float* bufA = (float*)d_ws;
        float* bufB = bufA + ND;
        hipLaunchKernelGGL(init_copy, dim3(copyGrid), dim3(blk), 0, stream,
                           (const float4*)vemb, (const float4*)demb,
                           (float4*)bufA, (float4*)out, nv4, total4);
        float* cur = bufA;
        float* nxt = bufB;
        for (int l = 0; l < 3; ++l) {
            hipMemsetAsync(nxt, 0, (size_t)ND * sizeof(float), stream);
            long threads = (long)E * 64;
            int  sgrid   = (int)((threads + blk - 1) / blk);
            hipLaunchKernelGGL(spmm_scatter, dim3(sgrid), dim3(blk), 0, stream,
                               erow, ecol, eval, cur, nxt, E);
            float s = (l == 2) ? 0.25f : 1.0f;
            hipLaunchKernelGGL(add_scale, dim3(copyGrid), dim3(blk), 0, stream,
                               (float4*)out, (const float4*)nxt, s, total4);
            float* t = cur; cur = nxt; nxt = t;
        }
    }
}

// Round 8
// 255.196 us; speedup vs baseline: 1.0424x; 1.0424x over previous
//
#include <hip/hip_runtime.h>
#include <hip/hip_fp16.h>

static constexpr int D = 128;
static constexpr int RPB_LOG = 10;           // 1024 rows per bin
static constexpr int RPB = 1 << RPB_LOG;
static constexpr int MAX_BINS = 1024;        // supports N <= 2^20 rows
static constexpr int CHUNK = 16384;          // edges per binA/binCount block

typedef float f32x4 __attribute__((ext_vector_type(4)));
__device__ __forceinline__ void nt_store4(float* p, float a, float b, float c, float d) {
    f32x4 v = {a, b, c, d};
    __builtin_nontemporal_store(v, (f32x4*)p);
}

// exclusive scan over 1024 threads; wsum = 16-int LDS scratch; 2 barriers.
__device__ __forceinline__ int excl_scan_1024(int v, int* wsum, int t) {
    int x = v;
#pragma unroll
    for (int off = 1; off < 64; off <<= 1) {
        int y = __shfl_up(x, off, 64);
        if ((t & 63) >= off) x += y;
    }
    int wid = t >> 6;
    if ((t & 63) == 63) wsum[wid] = x;
    __syncthreads();
    if (t < 16) {
        int w = wsum[t];
#pragma unroll
        for (int off = 1; off < 16; off <<= 1) {
            int y = __shfl_up(w, off, 64);
            if (t >= off) w += y;
        }
        wsum[t] = w;
    }
    __syncthreads();
    int base = (wid > 0) ? wsum[wid - 1] : 0;
    return base + x - v;
}

// ---------------- pass 0: count edges per bin ----------------
__global__ void binCount(const int* __restrict__ erow, int* __restrict__ bin_cnt,
                         int E, int nbins) {
    __shared__ int hist[MAX_BINS];
    int t = threadIdx.x;                       // 512
    int e0 = blockIdx.x * CHUNK;
    for (int i = t; i < nbins; i += 512) hist[i] = 0;
    __syncthreads();
    for (int k = 0; k < CHUNK / 512; ++k) {
        int e = e0 + t + k * 512;
        if (e < E) atomicAdd(&hist[erow[e] >> RPB_LOG], 1);
    }
    __syncthreads();
    for (int b = t; b < nbins; b += 512)
        if (hist[b]) atomicAdd(&bin_cnt[b], hist[b]);
}

// ---------------- pass 0b: exclusive scan of bin counts ----------------
__global__ void scanBins(const int* __restrict__ bin_cnt, int* __restrict__ bin_base,
                         int* __restrict__ gcur, int nbins, int E) {
    __shared__ int wsum[16];
    int t = threadIdx.x;                       // 1024
    int v = (t < nbins) ? bin_cnt[t] : 0;
    int excl = excl_scan_1024(v, wsum, t);
    if (t < nbins) {
        bin_base[t] = excl;
        gcur[t] = excl;
    }
    if (t == 0) bin_base[nbins] = E;
}

// ---------------- pass A: scatter packed (rin|col) into bin slices ----------------
__global__ void binA(const int* __restrict__ erow, const int* __restrict__ ecol,
                     int* __restrict__ gcur, int* __restrict__ tmp, int E, int nbins) {
    __shared__ int hist[MAX_BINS];
    __shared__ int base[MAX_BINS];
    __shared__ int lcur[MAX_BINS];
    int t = threadIdx.x;                       // 512
    int e0 = blockIdx.x * CHUNK;
    for (int i = t; i < nbins; i += 512) { hist[i] = 0; lcur[i] = 0; }
    __syncthreads();
    for (int k = 0; k < CHUNK / 512; ++k) {
        int e = e0 + t + k * 512;
        if (e < E) atomicAdd(&hist[erow[e] >> RPB_LOG], 1);
    }
    __syncthreads();
    for (int b = t; b < nbins; b += 512)
        base[b] = hist[b] ? atomicAdd(&gcur[b], hist[b]) : 0;
    __syncthreads();
    for (int k = 0; k < CHUNK / 512; ++k) {
        int e = e0 + t + k * 512;
        if (e < E) {
            int r = erow[e];
            int b = r >> RPB_LOG;
            int pos = base[b] + atomicAdd(&lcur[b], 1);
            tmp[pos] = ((r & (RPB - 1)) << 20) | ecol[e];
        }
    }
}

// ------- pass B: per-bin degree hist + scan + order + fused g0 init -------
__global__ void binB(const int* __restrict__ tmp, const int* __restrict__ bin_base,
                     int* __restrict__ row_ptr, float* __restrict__ dinv,
                     float* __restrict__ rdinv, int* __restrict__ col_s,
                     const float4* __restrict__ xv, const float4* __restrict__ xd,
                     int nvRows, __half* __restrict__ g0,
                     int N, int E, int nbins) {
    __shared__ int cnt[RPB];
    __shared__ int cur[RPB];
    __shared__ float dls[RPB];
    __shared__ int wsum[16];
    int b = blockIdx.x;
    int r0 = b << RPB_LOG;
    int t = threadIdx.x;                       // 1024
    cnt[t] = 0;
    __syncthreads();
    int start = bin_base[b];
    int end = bin_base[b + 1];
    for (int p = start + t; p < end; p += RPB)
        atomicAdd(&cnt[((unsigned)tmp[p]) >> 20], 1);
    __syncthreads();
    int deg = cnt[t];
    int rp = start + excl_scan_1024(deg, wsum, t);
    int r = r0 + t;
    float dv = (deg > 0) ? rsqrtf((float)deg) : 0.0f;
    if (r < N) {
        row_ptr[r] = rp;
        dinv[r] = dv;
        rdinv[r] = (deg > 0) ? sqrtf((float)deg) : 0.0f;
    }
    if (b == 0 && t == 0) row_ptr[N] = E;
    cur[t] = rp;
    dls[t] = dv;
    __syncthreads();
    for (int p = start + t; p < end; p += RPB) {
        unsigned v = (unsigned)tmp[p];
        int pos = atomicAdd(&cur[v >> 20], 1);
        col_s[pos] = (int)(v & 0xFFFFF);
    }
    // fused init: g0[r] = fp16(dinv[r] * x[r]) for rows of this bin.
    // Each thread handles 8 floats (2 float4 reads -> 1 float4-of-halves write).
    for (int idx = t; idx < RPB * 16; idx += RPB) {
        int rr = r0 + (idx >> 4);
        if (rr >= N) break;
        int q = idx & 15;
        float w = dls[idx >> 4];
        const float4* src = (rr < nvRows) ? (xv + (long)rr * 32)
                                          : (xd + (long)(rr - nvRows) * 32);
        float4 a = src[q * 2];
        float4 c = src[q * 2 + 1];
        float4 st;
        __half2* hs = (__half2*)&st;
        hs[0] = __floats2half2_rn(w * a.x, w * a.y);
        hs[1] = __floats2half2_rn(w * a.z, w * a.w);
        hs[2] = __floats2half2_rn(w * c.x, w * c.y);
        hs[3] = __floats2half2_rn(w * c.z, w * c.w);
        ((float4*)(g0 + (long)rr * D))[q] = st;
    }
}

// Gather core: 4 lane-groups of 16; each group fetches whole 256B g-rows
// (one dwordx4/lane), 2 rows in flight per group; butterfly-reduce groups.
__device__ __forceinline__ void gather_rows(const int* __restrict__ col_s,
                                            int start, int end,
                                            const __half* __restrict__ gsrc,
                                            int grp, int sub, float acc[8]) {
    int j = start + grp;
    for (; j + 4 < end; j += 8) {
        int c0 = col_s[j];
        int c1 = col_s[j + 4];
        float4 v0 = ((const float4*)(gsrc + (long)c0 * D))[sub];
        float4 v1 = ((const float4*)(gsrc + (long)c1 * D))[sub];
        const __half2* h0 = (const __half2*)&v0;
        const __half2* h1 = (const __half2*)&v1;
#pragma unroll
        for (int k = 0; k < 4; ++k) {
            float2 f0 = __half22float2(h0[k]);
            float2 f1 = __half22float2(h1[k]);
            acc[2 * k]     += f0.x + f1.x;
            acc[2 * k + 1] += f0.y + f1.y;
        }
    }
    if (j < end) {
        int c = col_s[j];
        float4 v = ((const float4*)(gsrc + (long)c * D))[sub];
        const __half2* h = (const __half2*)&v;
#pragma unroll
        for (int k = 0; k < 4; ++k) {
            float2 f = __half22float2(h[k]);
            acc[2 * k]     += f.x;
            acc[2 * k + 1] += f.y;
        }
    }
#pragma unroll
    for (int k = 0; k < 8; ++k) {
        acc[k] += __shfl_xor(acc[k], 16, 64);
        acc[k] += __shfl_xor(acc[k], 32, 64);
    }
}

// ---------------- mid layers: gnext = fp16(dinv^2 * sum_c g[c]) ----------------
__global__ void spmm_mid(const int* __restrict__ row_ptr, const int* __restrict__ col_s,
                         const float* __restrict__ dinv, const __half* __restrict__ g,
                         __half* __restrict__ gnext, int N) {
    int gid = blockIdx.x * blockDim.x + threadIdx.x;
    int r = __builtin_amdgcn_readfirstlane(gid >> 6);
    if (r >= N) return;
    int lane = gid & 63;
    int grp = lane >> 4, sub = lane & 15;
    int start = row_ptr[r], end = row_ptr[r + 1];
    float acc[8] = {0, 0, 0, 0, 0, 0, 0, 0};
    gather_rows(col_s, start, end, g, grp, sub, acc);
    if (lane < 16) {
        float dr = dinv[r];
        float d2 = dr * dr;
        float4 st;
        __half2* hs = (__half2*)&st;
#pragma unroll
        for (int k = 0; k < 4; ++k)
            hs[k] = __floats2half2_rn(d2 * acc[2 * k], d2 * acc[2 * k + 1]);
        ((float4*)(gnext + (long)r * D))[sub] = st;
    }
}

// -------- final layer: out = 0.25*(x + (g1+g2)*rdinv + dinv*sum g2[c]) --------
__global__ void spmm_final(const int* __restrict__ row_ptr, const int* __restrict__ col_s,
                           const float* __restrict__ dinv, const float* __restrict__ rdinv,
                           const __half* __restrict__ g2,    // gather source
                           const __half* __restrict__ g1,    // layer-1 output
                           const float* __restrict__ xv, const float* __restrict__ xd,
                           int nvRows, float* __restrict__ out, int N) {
    int gid = blockIdx.x * blockDim.x + threadIdx.x;
    int r = __builtin_amdgcn_readfirstlane(gid >> 6);
    if (r >= N) return;
    int lane = gid & 63;
    int grp = lane >> 4, sub = lane & 15;
    int start = row_ptr[r], end = row_ptr[r + 1];
    float acc[8] = {0, 0, 0, 0, 0, 0, 0, 0};
    gather_rows(col_s, start, end, g2, grp, sub, acc);
    if (lane < 16) {
        float dr = dinv[r];
        float rd = rdinv[r];
        const float* xbase = (r < nvRows) ? (xv + (long)r * D)
                                          : (xd + (long)(r - nvRows) * D);
        float4 x0 = ((const float4*)xbase)[sub * 2];
        float4 x1 = ((const float4*)xbase)[sub * 2 + 1];
        float4 p1v = ((const float4*)(g1 + (long)r * D))[sub];
        float4 p2v = ((const float4*)(g2 + (long)r * D))[sub];
        const __half2* h1 = (const __half2*)&p1v;
        const __half2* h2 = (const __half2*)&p2v;
        float xr[8] = {x0.x, x0.y, x0.z, x0.w, x1.x, x1.y, x1.z, x1.w};
        float o[8];
#pragma unroll
        for (int k = 0; k < 4; ++k) {
            float2 f1 = __half22float2(h1[k]);
            float2 f2 = __half22float2(h2[k]);
            o[2 * k]     = 0.25f * (xr[2 * k]     + (f1.x + f2.x) * rd + dr * acc[2 * k]);
            o[2 * k + 1] = 0.25f * (xr[2 * k + 1] + (f1.y + f2.y) * rd + dr * acc[2 * k + 1]);
        }
        float* ob = out + (long)r * D + sub * 8;
        nt_store4(ob,     o[0], o[1], o[2], o[3]);
        nt_store4(ob + 4, o[4], o[5], o[6], o[7]);
    }
}

// ---------------- fallback (atomic scatter path, fp32) ----------------
__global__ void init_copy(const float4* __restrict__ vsrc,
                          const float4* __restrict__ dsrc,
                          float4* __restrict__ h,
                          float4* __restrict__ acc,
                          long nv4, long total4) {
    long i = (long)blockIdx.x * blockDim.x + threadIdx.x;
    long stride = (long)gridDim.x * blockDim.x;
    for (; i < total4; i += stride) {
        float4 v = (i < nv4) ? vsrc[i] : dsrc[i - nv4];
        h[i] = v;
        acc[i] = v;
    }
}

__global__ void spmm_scatter(const int* __restrict__ erow, const int* __restrict__ ecol,
                             const float* __restrict__ eval, const float* __restrict__ h,
                             float* __restrict__ hnext, int E) {
    long tid = (long)blockIdx.x * blockDim.x + threadIdx.x;
    int e = (int)(tid >> 6);
    if (e >= E) return;
    int lane = (int)(tid & 63);
    int r = erow[e], c = ecol[e];
    float w = eval[e];
    const float2* src = reinterpret_cast<const float2*>(h + (long)c * D);
    float2 m = src[lane];
    float* dst = hnext + (long)r * D + lane * 2;
    atomicAdd(dst, w * m.x);
    atomicAdd(dst + 1, w * m.y);
}

__global__ void add_scale(float4* __restrict__ acc, const float4* __restrict__ b,
                          float s, long total4) {
    long i = (long)blockIdx.x * blockDim.x + threadIdx.x;
    long stride = (long)gridDim.x * blockDim.x;
    for (; i < total4; i += stride) {
        float4 a = acc[i];
        float4 v = b[i];
        a.x = (a.x + v.x) * s;
        a.y = (a.y + v.y) * s;
        a.z = (a.z + v.z) * s;
        a.w = (a.w + v.w) * s;
        acc[i] = a;
    }
}

extern "C" void kernel_launch(void* const* d_in, const int* in_sizes, int n_in,
                              void* d_out, int out_size, void* d_ws, size_t ws_size,
                              hipStream_t stream) {
    const int*   erow = (const int*)d_in[0];
    const int*   ecol = (const int*)d_in[1];
    const float* eval = (const float*)d_in[2];
    const float* vemb = (const float*)d_in[3];
    const float* demb = (const float*)d_in[4];

    int  E   = in_sizes[0];
    long nvD = in_sizes[3];
    long ndD = in_sizes[4];
    long ND  = nvD + ndD;
    int  N   = (int)(ND / D);
    int  nvRows = (int)(nvD / D);
    int  nbins = (N + RPB - 1) >> RPB_LOG;

    float* out = (float*)d_out;

    // ws layout (fast path)
    char* w = (char*)d_ws;
    __half* gA = (__half*)w;  w += (size_t)ND * sizeof(__half);   // g0
    __half* gB = (__half*)w;  w += (size_t)ND * sizeof(__half);   // g1
    __half* gC = (__half*)w;  w += (size_t)ND * sizeof(__half);   // g2
    int* col_s    = (int*)w;  w += (size_t)E * sizeof(int);
    int* tmp      = (int*)w;  w += (size_t)E * sizeof(int);       // packed rin|col
    int* row_ptr  = (int*)w;  w += (size_t)(N + 1) * sizeof(int);
    int* bin_cnt  = (int*)w;  w += MAX_BINS * sizeof(int);
    int* bin_base = (int*)w;  w += (MAX_BINS + 1) * sizeof(int);
    int* gcur     = (int*)w;  w += MAX_BINS * sizeof(int);
    float* dinv   = (float*)w; w += (size_t)N * sizeof(float);
    float* rdinv  = (float*)w; w += (size_t)N * sizeof(float);
    size_t needed = (size_t)(w - (char*)d_ws);

    long total4 = ND / 4;
    long nv4    = nvD / 4;
    const int blk = 256;
    const int copyGrid = 2048;

    if (needed <= ws_size && nbins <= MAX_BINS && N <= (1 << 20)) {
        // ---------- CSR build (bin-local, packed tmp, fused init) ----------
        hipMemsetAsync(bin_cnt, 0, (size_t)nbins * sizeof(int), stream);
        int nblkA = (E + CHUNK - 1) / CHUNK;
        hipLaunchKernelGGL(binCount, dim3(nblkA), dim3(512), 0, stream,
                           erow, bin_cnt, E, nbins);
        hipLaunchKernelGGL(scanBins, dim3(1), dim3(1024), 0, stream,
                           bin_cnt, bin_base, gcur, nbins, E);
        hipLaunchKernelGGL(binA, dim3(nblkA), dim3(512), 0, stream,
                           erow, ecol, gcur, tmp, E, nbins);
        hipLaunchKernelGGL(binB, dim3(nbins), dim3(RPB), 0, stream,
                           tmp, bin_base, row_ptr, dinv, rdinv, col_s,
                           (const float4*)vemb, (const float4*)demb,
                           nvRows, gA, N, E, nbins);

        // ---------- layers ----------
        int rgrid = (int)(((long)N * 64 + blk - 1) / blk);
        hipLaunchKernelGGL(spmm_mid, dim3(rgrid), dim3(blk), 0, stream,
                           row_ptr, col_s, dinv, gA, gB, N);
        hipLaunchKernelGGL(spmm_mid, dim3(rgrid), dim3(blk), 0, stream,
                           row_ptr, col_s, dinv, gB, gC, N);
        hipLaunchKernelGGL(spmm_final, dim3(rgrid), dim3(blk), 0, stream,
                           row_ptr, col_s, dinv, rdinv, gC, gB,
                           vemb, demb, nvRows, out, N);
    } else {
        // ---------- fallback: atomic scatter path (fp32) ----------
        float* bufA = (float*)d_ws;
        float* bufB = bufA + ND;
        hipLaunchKernelGGL(init_copy, dim3(copyGrid), dim3(blk), 0, stream,
                           (const float4*)vemb, (const float4*)demb,
                           (float4*)bufA, (float4*)out, nv4, total4);
        float* cur = bufA;
        float* nxt = bufB;
        for (int l = 0; l < 3; ++l) {
            hipMemsetAsync(nxt, 0, (size_t)ND * sizeof(float), stream);
            long threads = (long)E * 64;
            int  sgrid   = (int)((threads + blk - 1) / blk);
            hipLaunchKernelGGL(spmm_scatter, dim3(sgrid), dim3(blk), 0, stream,
                               erow, ecol, eval, cur, nxt, E);
            float s = (l == 2) ? 0.25f : 1.0f;
            hipLaunchKernelGGL(add_scale, dim3(copyGrid), dim3(blk), 0, stream,
                               (float4*)out, (const float4*)nxt, s, total4);
            float* t = cur; cur = nxt; nxt = t;
        }
    }
}